// Round 13
// baseline (225.972 us; speedup 1.0000x reference)
//
#include <hip/hip_runtime.h>

typedef __attribute__((ext_vector_type(8))) short bf16x8;
typedef __attribute__((ext_vector_type(4))) float f32x4;

#define MFMA16(a, b, c) __builtin_amdgcn_mfma_f32_16x16x32_bf16(a, b, c, 0, 0, 0)

__device__ inline short f2bf(float f) {
  union { float f; unsigned u; } v;
  v.f = f;
  unsigned r = v.u + 0x7FFF + ((v.u >> 16) & 1);
  return (short)(r >> 16);
}
__device__ inline float bf2f(short s) {
  union { unsigned u; float f; } v;
  v.u = ((unsigned)(unsigned short)s) << 16;
  return v.f;
}
#define GLD_LDS16(g, l)                                                        \
  __builtin_amdgcn_global_load_lds(                                            \
      (const __attribute__((address_space(1))) unsigned int*)(g),              \
      (__attribute__((address_space(3))) unsigned int*)(l), 16, 0, 0)

__device__ __forceinline__ void raw_barrier() {
  __asm__ volatile("" ::: "memory");
  __builtin_amdgcn_s_barrier();
  __asm__ volatile("" ::: "memory");
}

// ---------------- prep: x->bf16 + weight transposes + fused qkv bias vector ----------------
__global__ __launch_bounds__(256) void prep_kernel(
    const float* __restrict__ x, const float* __restrict__ q_w,
    const float* __restrict__ k_w, const float* __restrict__ v_w,
    const float* __restrict__ o_w, const float* __restrict__ q_b,
    const float* __restrict__ k_b, const float* __restrict__ v_b,
    short* __restrict__ xb, short* __restrict__ wqkv_t, short* __restrict__ wo_t,
    float* __restrict__ biasAll) {
  __shared__ float t[64][65];
  int bid = blockIdx.x;
  if (bid == 6400) {  // fused bias vector [q_b | k_b | v_b]
    for (int i = threadIdx.x; i < 2560; i += 256) {
      float v = (i < 2048) ? q_b[i] : (i < 2304 ? k_b[i - 2048] : v_b[i - 2304]);
      biasAll[i] = v;
    }
    return;
  }
  if (bid < 4096) {  // cvt x
    int i = (bid * 256 + threadIdx.x) * 4;
    float4 f = *(const float4*)&x[i];
    short4 o;
    o.x = f2bf(f.x); o.y = f2bf(f.y); o.z = f2bf(f.z); o.w = f2bf(f.w);
    *(short4*)&xb[i] = o;
    return;
  }
  bid -= 4096;
  const float* src;
  short* dst;
  int C, bx, by;
  if (bid < 1024) {
    src = q_w; dst = wqkv_t; C = 2048;
    bx = (bid & 31) * 64; by = (bid >> 5) * 64;
  } else if (bid < 1152) {
    bid -= 1024;
    src = k_w; dst = wqkv_t + (size_t)2048 * 2048; C = 256;
    bx = (bid & 3) * 64; by = (bid >> 2) * 64;
  } else if (bid < 1280) {
    bid -= 1152;
    src = v_w; dst = wqkv_t + (size_t)2304 * 2048; C = 256;
    bx = (bid & 3) * 64; by = (bid >> 2) * 64;
  } else {
    bid -= 1280;
    src = o_w; dst = wo_t; C = 2048;
    bx = (bid & 31) * 64; by = (bid >> 5) * 64;
  }
  const int R = 2048;
  const int tx = threadIdx.x & 15;
  const int ty = threadIdx.x >> 4;
#pragma unroll
  for (int i = 0; i < 4; i++) {
    int row = ty + i * 16;
    float4 f = *(const float4*)&src[(size_t)(by + row) * C + bx + tx * 4];
    t[row][tx * 4 + 0] = f.x;
    t[row][tx * 4 + 1] = f.y;
    t[row][tx * 4 + 2] = f.z;
    t[row][tx * 4 + 3] = f.w;
  }
  __syncthreads();
#pragma unroll
  for (int i = 0; i < 4; i++) {
    int c = ty + i * 16;
    short4 o;
    o.x = f2bf(t[tx * 4 + 0][c]);
    o.y = f2bf(t[tx * 4 + 1][c]);
    o.z = f2bf(t[tx * 4 + 2][c]);
    o.w = f2bf(t[tx * 4 + 3][c]);
    *(short4*)&dst[(size_t)(bx + c) * R + by + tx * 4] = o;
  }
}

// ---------------- QKV GEMM + K/V-only fused post ----------------
// Q blocks (xt<16, 512 of 640): plain bias + bf16 store to qkvb (attn does Q-post).
// K blocks (xt=16,17): Ts-stage -> rmsnorm+rope+mask -> ko, with 1-row-lookahead
//   cos/sin/mask prefetch (5 scalars; no VGPR cliff -- R11 lesson).
// V blocks (xt=18,19): Ts-stage -> mask+transpose -> vtb (R10-proven code).
// Numerics identical to the old postv_kv path: Ts holds the same f2bf(acc+bias) bf16.
__global__ __launch_bounds__(256) void gemm_qkv_kernel(
    const short* __restrict__ A, const short* __restrict__ B,
    short* __restrict__ Cs, const float* __restrict__ bias,
    const float* __restrict__ kg, const float* __restrict__ cosb,
    const float* __restrict__ sinb, const float* __restrict__ maskp,
    short* __restrict__ ko, short* __restrict__ vtb, int gx, int gy, int P) {
  __shared__ __align__(16) short sm[4 * 64 * 32 + 4 * 128 * 32];  // 48 KB As|Bs ring
#define AsP(st) (&sm[(st)*2048])
#define BsP(st) (&sm[8192 + (st)*4096])
  const int bid = blockIdx.x;
  const int xcd = bid & 7, idx = bid >> 3;
  const int colsPerX = gx >> 1, rowsPerX = gy >> 2;
  const int xt = (xcd & 1) * colsPerX + idx % colsPerX;
  const int yt = (xcd >> 1) * rowsPerX + idx / colsPerX;
  const int tid = threadIdx.x;
  const int lane = tid & 63, wave = tid >> 6;
  const int quad = lane >> 4, l16 = lane & 15;
  const int m0 = yt * 64, n0 = xt * 128;
  const int wm = (wave >> 1) * 32, wn = (wave & 1) * 64;
  const int r0 = tid >> 2, c0 = (tid & 3) * 8;
  const int ca = ((tid & 3) ^ ((r0 >> 1) & 3)) * 8;
  const size_t arow = (size_t)(m0 + r0) * 2048;
  const size_t brow0 = (size_t)(n0 + r0) * 2048, brow1 = (size_t)(n0 + r0 + 64) * 2048;
  f32x4 acc[2][4];
#pragma unroll
  for (int mi = 0; mi < 2; mi++)
#pragma unroll
    for (int ni = 0; ni < 4; ni++) acc[mi][ni] = (f32x4){0.f, 0.f, 0.f, 0.f};

#pragma unroll
  for (int st = 0; st < 4; st++) {
    const int kk = st * 32 + ca;
    GLD_LDS16(&A[arow + kk], AsP(st) + r0 * 32 + c0);
    GLD_LDS16(&B[brow0 + kk], BsP(st) + r0 * 32 + c0);
    GLD_LDS16(&B[brow1 + kk], BsP(st) + (r0 + 64) * 32 + c0);
  }

  const int sx = (l16 >> 1) & 3;
  for (int p = 0; p < P; p++) {
    if (p < P - 1) {
      __asm__ volatile("s_waitcnt vmcnt(6)" ::: "memory");
    } else {
      __asm__ volatile("s_waitcnt vmcnt(0)" ::: "memory");
    }
    raw_barrier();
#pragma unroll
    for (int j = 0; j < 2; j++) {
      const int cur = (2 * p + j) & 3;
      bf16x8 af[2], bfr[4];
#pragma unroll
      for (int mi = 0; mi < 2; mi++)
        af[mi] = *(const bf16x8*)(AsP(cur) + (wm + mi * 16 + l16) * 32 + ((quad ^ sx) * 8));
#pragma unroll
      for (int ni = 0; ni < 4; ni++)
        bfr[ni] = *(const bf16x8*)(BsP(cur) + (wn + ni * 16 + l16) * 32 + ((quad ^ sx) * 8));
#pragma unroll
      for (int mi = 0; mi < 2; mi++)
#pragma unroll
        for (int ni = 0; ni < 4; ni++)
          acc[mi][ni] = MFMA16(af[mi], bfr[ni], acc[mi][ni]);
    }
    __asm__ volatile("s_waitcnt lgkmcnt(0)" ::: "memory");
    raw_barrier();
    if (p < P - 2) {
#pragma unroll
      for (int j = 0; j < 2; j++) {
        const int st = 2 * p + 4 + j;
        const int slot = st & 3;
        const int kk = st * 32 + ca;
        GLD_LDS16(&A[arow + kk], AsP(slot) + r0 * 32 + c0);
        GLD_LDS16(&B[brow0 + kk], BsP(slot) + r0 * 32 + c0);
        GLD_LDS16(&B[brow1 + kk], BsP(slot) + (r0 + 64) * 32 + c0);
      }
    }
  }

  if (xt < 16) {  // Q: plain bias + bf16 store (attn fuses Q-post)
#pragma unroll
    for (int mi = 0; mi < 2; mi++)
#pragma unroll
      for (int ni = 0; ni < 4; ni++) {
        const int col = n0 + wn + ni * 16 + l16;
        const float bv = bias[col];
#pragma unroll
        for (int r = 0; r < 4; r++)
          Cs[(size_t)(m0 + wm + mi * 16 + quad * 4 + r) * 2560 + col] =
              f2bf(acc[mi][ni][r] + bv);
      }
    return;
  }

  // ---- K/V fused epilogue: stage bf16(acc+bias) into the dead LDS ring ----
  const int bb = m0 >> 10, sg = m0 & 1023;  // 64 | 1024: whole tile is one batch
  short* Ts = sm;                           // [64][136]
#pragma unroll
  for (int mi = 0; mi < 2; mi++)
#pragma unroll
    for (int ni = 0; ni < 4; ni++) {
      const int col = wn + ni * 16 + l16;
      const float bv = bias[n0 + col];
#pragma unroll
      for (int r = 0; r < 4; r++)
        Ts[(wm + mi * 16 + quad * 4 + r) * 136 + col] = f2bf(acc[mi][ni][r] + bv);
    }
  __syncthreads();

  if (xt < 18) {  // K: rmsnorm + rope + mask, 1-row-lookahead prefetch
    const int slot = xt - 16;
    const float g0 = kg[lane], g1 = kg[64 + lane];
    const int sel = (lane < 16) ? 0 : (lane < 40) ? 1 : 2;
    const size_t cbase = ((size_t)(sel * 2 + bb) * 1024 + sg + wave * 16) * 128 + lane;
    float c0n = cosb[cbase], s0n = sinb[cbase];
    float c1n = cosb[cbase + 64], s1n = sinb[cbase + 64];
    float mkn = maskp[m0 + wave * 16];
#pragma unroll
    for (int i = 0; i < 16; i++) {
      const float c0v = c0n, s0v = s0n, c1v = c1n, s1v = s1n, mk = mkn;
      if (i < 15) {  // prefetch next row while this row computes
        const size_t cn = cbase + (size_t)(i + 1) * 128;
        c0n = cosb[cn]; s0n = sinb[cn];
        c1n = cosb[cn + 64]; s1n = sinb[cn + 64];
        mkn = maskp[m0 + wave * 16 + i + 1];
      }
      const int row = wave * 16 + i;
      const int s = sg + row;
      float v0 = bf2f(Ts[row * 136 + lane]);
      float v1 = bf2f(Ts[row * 136 + 64 + lane]);
      float ssum = v0 * v0 + v1 * v1;
#pragma unroll
      for (int o = 1; o < 64; o <<= 1) ssum += __shfl_xor(ssum, o);
      const float rr = rsqrtf(ssum * (1.0f / 128.0f) + 1e-6f);
      v0 = g0 * v0 * rr;
      v1 = g1 * v1 * rr;
      const float o0 = (v0 * c0v - v1 * s0v) * mk;
      const float o1 = (v1 * c1v + v0 * s1v) * mk;
      short* dst = ko + (((size_t)(bb * 2 + slot) * 1024) + s) * 128;
      dst[lane] = f2bf(o0);
      dst[64 + lane] = f2bf(o1);
    }
  } else {  // V: mask + transpose to vtb[(b*2+kv)*128+d][s]
    const int kvs = xt - 18;
    const int d = tid >> 1;
    const int sb = (tid & 1) * 32;
    short tmp[32];
#pragma unroll
    for (int i = 0; i < 32; i++) {
      const int srow = sb + i;
      tmp[i] = f2bf(bf2f(Ts[srow * 136 + d]) * maskp[m0 + srow]);
    }
    short* dst = vtb + ((size_t)(bb * 2 + kvs) * 128 + d) * 1024 + sg + sb;
#pragma unroll
    for (int j = 0; j < 4; j++) *(int4*)&dst[j * 8] = *(const int4*)&tmp[j * 8];
  }
#undef AsP
#undef BsP
}

// ---------------- bf16 GEMM, 64x128 tile, ring-4, f32 out (o-proj) ----------------
__global__ __launch_bounds__(256) void gemm_db_kernel(const short* __restrict__ A,
                                                      const short* __restrict__ B,
                                                      float* __restrict__ C, int N,
                                                      int gx, int gy, int P) {
  __shared__ __align__(16) short As[4][64 * 32];
  __shared__ __align__(16) short Bs[4][128 * 32];
  const int bid = blockIdx.x;
  const int xcd = bid & 7, idx = bid >> 3;
  const int colsPerX = gx >> 1, rowsPerX = gy >> 2;
  const int xt = (xcd & 1) * colsPerX + idx % colsPerX;
  const int yt = (xcd >> 1) * rowsPerX + idx / colsPerX;
  const int tid = threadIdx.x;
  const int lane = tid & 63, wave = tid >> 6;
  const int quad = lane >> 4, l16 = lane & 15;
  const int m0 = yt * 64, n0 = xt * 128;
  const int wm = (wave >> 1) * 32, wn = (wave & 1) * 64;
  const int r0 = tid >> 2, c0 = (tid & 3) * 8;
  const int ca = ((tid & 3) ^ ((r0 >> 1) & 3)) * 8;
  const size_t arow = (size_t)(m0 + r0) * 2048;
  const size_t brow0 = (size_t)(n0 + r0) * 2048, brow1 = (size_t)(n0 + r0 + 64) * 2048;
  f32x4 acc[2][4];
#pragma unroll
  for (int mi = 0; mi < 2; mi++)
#pragma unroll
    for (int ni = 0; ni < 4; ni++) acc[mi][ni] = (f32x4){0.f, 0.f, 0.f, 0.f};

#pragma unroll
  for (int st = 0; st < 4; st++) {
    const int kk = st * 32 + ca;
    GLD_LDS16(&A[arow + kk], &As[st][r0 * 32 + c0]);
    GLD_LDS16(&B[brow0 + kk], &Bs[st][r0 * 32 + c0]);
    GLD_LDS16(&B[brow1 + kk], &Bs[st][(r0 + 64) * 32 + c0]);
  }

  const int sx = (l16 >> 1) & 3;
  for (int p = 0; p < P; p++) {
    if (p < P - 1) {
      __asm__ volatile("s_waitcnt vmcnt(6)" ::: "memory");
    } else {
      __asm__ volatile("s_waitcnt vmcnt(0)" ::: "memory");
    }
    raw_barrier();
#pragma unroll
    for (int j = 0; j < 2; j++) {
      const int cur = (2 * p + j) & 3;
      bf16x8 af[2], bfr[4];
#pragma unroll
      for (int mi = 0; mi < 2; mi++)
        af[mi] = *(const bf16x8*)&As[cur][(wm + mi * 16 + l16) * 32 + ((quad ^ sx) * 8)];
#pragma unroll
      for (int ni = 0; ni < 4; ni++)
        bfr[ni] = *(const bf16x8*)&Bs[cur][(wn + ni * 16 + l16) * 32 + ((quad ^ sx) * 8)];
#pragma unroll
      for (int mi = 0; mi < 2; mi++)
#pragma unroll
        for (int ni = 0; ni < 4; ni++)
          acc[mi][ni] = MFMA16(af[mi], bfr[ni], acc[mi][ni]);
    }
    __asm__ volatile("s_waitcnt lgkmcnt(0)" ::: "memory");
    raw_barrier();
    if (p < P - 2) {
#pragma unroll
      for (int j = 0; j < 2; j++) {
        const int st = 2 * p + 4 + j;
        const int slot = st & 3;
        const int kk = st * 32 + ca;
        GLD_LDS16(&A[arow + kk], &As[slot][r0 * 32 + c0]);
        GLD_LDS16(&B[brow0 + kk], &Bs[slot][r0 * 32 + c0]);
        GLD_LDS16(&B[brow1 + kk], &Bs[slot][(r0 + 64) * 32 + c0]);
      }
    }
  }
#pragma unroll
  for (int mi = 0; mi < 2; mi++)
#pragma unroll
    for (int ni = 0; ni < 4; ni++)
#pragma unroll
      for (int r = 0; r < 4; r++)
        C[(size_t)(m0 + wm + mi * 16 + quad * 4 + r) * N + n0 + wn + ni * 16 + l16] =
            acc[mi][ni][r];
}

// ---------------- flash attention + FUSED Q-post (rmsnorm+rope in-register) ----------------
__global__ __launch_bounds__(256) void attn_kernel(
    const short* __restrict__ qkvb, const short* __restrict__ K,
    const short* __restrict__ Vt_g, const float* __restrict__ qg,
    const float* __restrict__ cosb, const float* __restrict__ sinb,
    short* __restrict__ attn) {
  const int qt = 15 - (int)blockIdx.x;
  const int h = blockIdx.y;
  const int b = blockIdx.z;
  const int nsteps = qt + 1;

  const int kv = h >> 3;
  const int tid = threadIdx.x;
  const int wave = tid >> 6, lane = tid & 63;
  const int quad = lane >> 4, l16 = lane & 15;
  __shared__ __align__(16) short Ks[2][64 * 128];
  __shared__ __align__(16) short Vs[2][128 * 64];
  __shared__ __align__(16) short Ps[4][16 * 72];

  const size_t koff = ((size_t)(b * 2 + kv) * 1024) * 128;
  const size_t voff = koff;
  const float scale = 0.08838834764831845f;  // 1/sqrt(128)

#define STAGE_KV(bf, ks0)                                                          \
  {                                                                                \
    _Pragma("unroll") for (int it = 0; it < 4; it++) {                             \
      const int c = it * 256 + tid;                                                \
      const int row = c >> 4, sl = c & 15;                                         \
      GLD_LDS16(&K[koff + (size_t)((ks0) + row) * 128 + ((sl ^ (row & 7)) * 8)],   \
                &Ks[bf][c * 8]);                                                   \
      const int d = c >> 3, sv = c & 7;                                            \
      GLD_LDS16(&Vt_g[voff + (size_t)d * 1024 + (ks0) + ((sv ^ (d & 7)) * 8)],     \
                &Vs[bf][c * 8]);                                                   \
    }                                                                              \
  }

  STAGE_KV(0, 0);  // step-0 staging in flight while Q-post computes below

  // ---- fused Q-post ----
  const int s = qt * 64 + wave * 16 + l16;  // this lane's row (seq pos)
  const short* qrow = qkvb + ((size_t)(b * 1024 + s)) * 2560 + h * 128;
  bf16x8 qraw[4];
#pragma unroll
  for (int kk = 0; kk < 4; kk++) qraw[kk] = *(const bf16x8*)&qrow[kk * 32 + quad * 8];
  float vq[4][8];
  float ss = 0.f;
#pragma unroll
  for (int kk = 0; kk < 4; kk++)
#pragma unroll
    for (int e = 0; e < 8; e++) {
      vq[kk][e] = bf2f(qraw[kk][e]);
      ss = fmaf(vq[kk][e], vq[kk][e], ss);
    }
  ss += __shfl_xor(ss, 16);
  ss += __shfl_xor(ss, 32);
  const float rr = rsqrtf(ss * (1.0f / 128.0f) + 1e-6f);
#pragma unroll
  for (int kk = 0; kk < 4; kk++) {
    float4 ga = *(const float4*)&qg[kk * 32 + quad * 8];
    float4 gb = *(const float4*)&qg[kk * 32 + quad * 8 + 4];
    vq[kk][0] *= ga.x * rr; vq[kk][1] *= ga.y * rr;
    vq[kk][2] *= ga.z * rr; vq[kk][3] *= ga.w * rr;
    vq[kk][4] *= gb.x * rr; vq[kk][5] *= gb.y * rr;
    vq[kk][6] *= gb.z * rr; vq[kk][7] *= gb.w * rr;
  }
  bf16x8 aq[4];
#pragma unroll
  for (int kk = 0; kk < 2; kk++) {  // rope pair (kk, kk+2): dims d and d+64
    const int dbase = kk * 32 + quad * 8;  // < 64; 8-group doesn't straddle 16/40
    const int sel = (dbase < 16) ? 0 : (dbase < 40) ? 1 : 2;
    const size_t ci = ((size_t)(sel * 2 + b) * 1024 + s) * 128 + dbase;
    float cd[8], sd[8], cD[8], sD[8];
    {
      float4 a0 = *(const float4*)&cosb[ci], a1 = *(const float4*)&cosb[ci + 4];
      cd[0]=a0.x; cd[1]=a0.y; cd[2]=a0.z; cd[3]=a0.w;
      cd[4]=a1.x; cd[5]=a1.y; cd[6]=a1.z; cd[7]=a1.w;
    }
    {
      float4 a0 = *(const float4*)&sinb[ci], a1 = *(const float4*)&sinb[ci + 4];
      sd[0]=a0.x; sd[1]=a0.y; sd[2]=a0.z; sd[3]=a0.w;
      sd[4]=a1.x; sd[5]=a1.y; sd[6]=a1.z; sd[7]=a1.w;
    }
    {
      float4 a0 = *(const float4*)&cosb[ci + 64], a1 = *(const float4*)&cosb[ci + 68];
      cD[0]=a0.x; cD[1]=a0.y; cD[2]=a0.z; cD[3]=a0.w;
      cD[4]=a1.x; cD[5]=a1.y; cD[6]=a1.z; cD[7]=a1.w;
    }
    {
      float4 a0 = *(const float4*)&sinb[ci + 64], a1 = *(const float4*)&sinb[ci + 68];
      sD[0]=a0.x; sD[1]=a0.y; sD[2]=a0.z; sD[3]=a0.w;
      sD[4]=a1.x; sD[5]=a1.y; sD[6]=a1.z; sD[7]=a1.w;
    }
#pragma unroll
    for (int e = 0; e < 8; e++) {
      aq[kk][e] = f2bf(vq[kk][e] * cd[e] - vq[kk + 2][e] * sd[e]);
      aq[kk + 2][e] = f2bf(vq[kk + 2][e] * cD[e] + vq[kk][e] * sD[e]);
    }
  }

  f32x4 o[8];
#pragma unroll
  for (int i = 0; i < 8; i++) o[i] = (f32x4){0.f, 0.f, 0.f, 0.f};
  float l[4] = {0.f, 0.f, 0.f, 0.f};
  const int qrow0 = qt * 64 + wave * 16 + quad * 4;

  for (int st = 0; st < nsteps; st++) {
    __asm__ volatile("s_waitcnt vmcnt(0)" ::: "memory");
    raw_barrier();
    if (st + 1 < nsteps) { STAGE_KV((st + 1) & 1, (st + 1) * 64); }
    const int cb = st & 1;
    const int ks0 = st * 64;
    f32x4 sc[4];
#pragma unroll
    for (int nt = 0; nt < 4; nt++) sc[nt] = (f32x4){0.f, 0.f, 0.f, 0.f};
    __builtin_amdgcn_s_setprio(1);
#pragma unroll
    for (int nt = 0; nt < 4; nt++) {
      const int rrK = nt * 16 + l16;
#pragma unroll
      for (int kk = 0; kk < 4; kk++) {
        bf16x8 bk = *(const bf16x8*)&Ks[cb][rrK * 128 + (((kk * 4 + quad) ^ (rrK & 7)) * 8)];
        sc[nt] = MFMA16(aq[kk], bk, sc[nt]);
      }
    }
    __builtin_amdgcn_s_setprio(0);
    // fixed-shift softmax weights: p = exp(s*scale - 12), causal-masked to 0
    short* P = &Ps[wave][0];
#pragma unroll
    for (int nt = 0; nt < 4; nt++) {
      const int kcol = ks0 + nt * 16 + l16;
#pragma unroll
      for (int r = 0; r < 4; r++) {
        float p = (kcol > qrow0 + r) ? 0.f : __expf(fmaf(sc[nt][r], scale, -12.0f));
        l[r] += p;
        P[(quad * 4 + r) * 72 + nt * 16 + l16] = f2bf(p);
      }
    }
    __asm__ volatile("s_waitcnt lgkmcnt(0)" ::: "memory");
    bf16x8 pa0 = *(const bf16x8*)&P[l16 * 72 + quad * 8];
    bf16x8 pa1 = *(const bf16x8*)&P[l16 * 72 + 32 + quad * 8];
    __builtin_amdgcn_s_setprio(1);
#pragma unroll
    for (int nt = 0; nt < 8; nt++) {
      const int rrV = nt * 16 + l16;
      bf16x8 bv0 = *(const bf16x8*)&Vs[cb][rrV * 64 + ((quad ^ (rrV & 7)) * 8)];
      bf16x8 bv1 = *(const bf16x8*)&Vs[cb][rrV * 64 + (((4 + quad) ^ (rrV & 7)) * 8)];
      o[nt] = MFMA16(pa0, bv0, o[nt]);
      o[nt] = MFMA16(pa1, bv1, o[nt]);
    }
    __builtin_amdgcn_s_setprio(0);
  }
#undef STAGE_KV
#pragma unroll
  for (int off = 1; off < 16; off <<= 1)
#pragma unroll
    for (int r = 0; r < 4; r++) l[r] += __shfl_xor(l[r], off);
  float inv[4];
#pragma unroll
  for (int r = 0; r < 4; r++) inv[r] = 1.f / l[r];
  const int lrow = wave * 16 + quad * 4;
  short* dst = attn + ((size_t)(b * 1024 + qt * 64 + lrow)) * 2048 + h * 128;
#pragma unroll
  for (int nt = 0; nt < 8; nt++)
#pragma unroll
    for (int r = 0; r < 4; r++)
      dst[(size_t)r * 2048 + nt * 16 + l16] = f2bf(o[nt][r] * inv[r]);
}

extern "C" void kernel_launch(void* const* d_in, const int* in_sizes, int n_in,
                              void* d_out, int out_size, void* d_ws, size_t ws_size,
                              hipStream_t stream) {
  const float* x = (const float*)d_in[0];
  const float* cosb = (const float*)d_in[1];
  const float* sinb = (const float*)d_in[2];
  const float* mask = (const float*)d_in[3];
  const float* q_w = (const float*)d_in[4];
  const float* q_b = (const float*)d_in[5];
  const float* k_w = (const float*)d_in[6];
  const float* k_b = (const float*)d_in[7];
  const float* v_w = (const float*)d_in[8];
  const float* v_b = (const float*)d_in[9];
  const float* qg = (const float*)d_in[10];
  const float* kg = (const float*)d_in[11];
  const float* o_w = (const float*)d_in[12];
  float* out = (float*)d_out;

  char* ws = (char*)d_ws;
  short* wo_t = (short*)(ws);                              // [0,8) MB
  short* wqkv_t = (short*)(ws + ((size_t)8 << 20));        // [8,18.4) MB (dead after gemm)
  short* attn = (short*)(ws + ((size_t)9 << 20));          // aliases wqkv_t (after gemm)
  short* xb = (short*)(ws + ((size_t)18 << 20));           // [18,26.4) MB
  short* kb = (short*)(ws + ((size_t)46 << 20));           // [46,47)
  short* vtb = (short*)(ws + ((size_t)47 << 20));          // [47,48)
  short* qkvb = (short*)(ws + ((size_t)48 << 20));         // [48,58.4) MB bf16 qkv
  float* biasAll = (float*)(ws + ((size_t)68 << 20));      // 10 KB fused bias

  prep_kernel<<<6401, 256, 0, stream>>>(x, q_w, k_w, v_w, o_w, q_b, k_b, v_b, xb,
                                        wqkv_t, wo_t, biasAll);
  gemm_qkv_kernel<<<640, 256, 0, stream>>>(xb, wqkv_t, qkvb, biasAll, kg, cosb, sinb,
                                           mask, kb, vtb, 20, 32, 32);
  attn_kernel<<<dim3(16, 16, 2), 256, 0, stream>>>(qkvb, kb, vtb, qg, cosb, sinb, attn);
  gemm_db_kernel<<<512, 256, 0, stream>>>(attn, wo_t, out, 2048, 16, 32, 32);
}

// Round 14
// 221.974 us; speedup vs baseline: 1.0180x; 1.0180x over previous
//
#include <hip/hip_runtime.h>

typedef __attribute__((ext_vector_type(8))) short bf16x8;
typedef __attribute__((ext_vector_type(4))) float f32x4;

#define MFMA16(a, b, c) __builtin_amdgcn_mfma_f32_16x16x32_bf16(a, b, c, 0, 0, 0)

__device__ inline short f2bf(float f) {
  union { float f; unsigned u; } v;
  v.f = f;
  unsigned r = v.u + 0x7FFF + ((v.u >> 16) & 1);
  return (short)(r >> 16);
}
__device__ inline float bf2f(short s) {
  union { unsigned u; float f; } v;
  v.u = ((unsigned)(unsigned short)s) << 16;
  return v.f;
}
#define GLD_LDS16(g, l)                                                        \
  __builtin_amdgcn_global_load_lds(                                            \
      (const __attribute__((address_space(1))) unsigned int*)(g),              \
      (__attribute__((address_space(3))) unsigned int*)(l), 16, 0, 0)

__device__ __forceinline__ void raw_barrier() {
  __asm__ volatile("" ::: "memory");
  __builtin_amdgcn_s_barrier();
  __asm__ volatile("" ::: "memory");
}

// ---------------- prep: x->bf16 + weight transposes + fused qkv bias vector ----------------
__global__ __launch_bounds__(256) void prep_kernel(
    const float* __restrict__ x, const float* __restrict__ q_w,
    const float* __restrict__ k_w, const float* __restrict__ v_w,
    const float* __restrict__ o_w, const float* __restrict__ q_b,
    const float* __restrict__ k_b, const float* __restrict__ v_b,
    short* __restrict__ xb, short* __restrict__ wqkv_t, short* __restrict__ wo_t,
    float* __restrict__ biasAll) {
  __shared__ float t[64][65];
  int bid = blockIdx.x;
  if (bid == 6400) {  // fused bias vector [q_b | k_b | v_b]
    for (int i = threadIdx.x; i < 2560; i += 256) {
      float v = (i < 2048) ? q_b[i] : (i < 2304 ? k_b[i - 2048] : v_b[i - 2304]);
      biasAll[i] = v;
    }
    return;
  }
  if (bid < 4096) {  // cvt x
    int i = (bid * 256 + threadIdx.x) * 4;
    float4 f = *(const float4*)&x[i];
    short4 o;
    o.x = f2bf(f.x); o.y = f2bf(f.y); o.z = f2bf(f.z); o.w = f2bf(f.w);
    *(short4*)&xb[i] = o;
    return;
  }
  bid -= 4096;
  const float* src;
  short* dst;
  int C, bx, by;
  if (bid < 1024) {
    src = q_w; dst = wqkv_t; C = 2048;
    bx = (bid & 31) * 64; by = (bid >> 5) * 64;
  } else if (bid < 1152) {
    bid -= 1024;
    src = k_w; dst = wqkv_t + (size_t)2048 * 2048; C = 256;
    bx = (bid & 3) * 64; by = (bid >> 2) * 64;
  } else if (bid < 1280) {
    bid -= 1152;
    src = v_w; dst = wqkv_t + (size_t)2304 * 2048; C = 256;
    bx = (bid & 3) * 64; by = (bid >> 2) * 64;
  } else {
    bid -= 1280;
    src = o_w; dst = wo_t; C = 2048;
    bx = (bid & 31) * 64; by = (bid >> 5) * 64;
  }
  const int R = 2048;
  const int tx = threadIdx.x & 15;
  const int ty = threadIdx.x >> 4;
#pragma unroll
  for (int i = 0; i < 4; i++) {
    int row = ty + i * 16;
    float4 f = *(const float4*)&src[(size_t)(by + row) * C + bx + tx * 4];
    t[row][tx * 4 + 0] = f.x;
    t[row][tx * 4 + 1] = f.y;
    t[row][tx * 4 + 2] = f.z;
    t[row][tx * 4 + 3] = f.w;
  }
  __syncthreads();
#pragma unroll
  for (int i = 0; i < 4; i++) {
    int c = ty + i * 16;
    short4 o;
    o.x = f2bf(t[tx * 4 + 0][c]);
    o.y = f2bf(t[tx * 4 + 1][c]);
    o.z = f2bf(t[tx * 4 + 2][c]);
    o.w = f2bf(t[tx * 4 + 3][c]);
    *(short4*)&dst[(size_t)(bx + c) * R + by + tx * 4] = o;
  }
}

// ---------------- QKV GEMM: 64x128 tile, ring-4, bias + bf16 epilogue ----------------
__global__ __launch_bounds__(256) void gemm_qkv_kernel(const short* __restrict__ A,
                                                       const short* __restrict__ B,
                                                       short* __restrict__ Cs,
                                                       const float* __restrict__ bias,
                                                       int N, int gx, int gy, int P) {
  __shared__ __align__(16) short As[4][64 * 32];
  __shared__ __align__(16) short Bs[4][128 * 32];
  const int bid = blockIdx.x;
  const int xcd = bid & 7, idx = bid >> 3;
  const int colsPerX = gx >> 1, rowsPerX = gy >> 2;
  const int xt = (xcd & 1) * colsPerX + idx % colsPerX;
  const int yt = (xcd >> 1) * rowsPerX + idx / colsPerX;
  const int tid = threadIdx.x;
  const int lane = tid & 63, wave = tid >> 6;
  const int quad = lane >> 4, l16 = lane & 15;
  const int m0 = yt * 64, n0 = xt * 128;
  const int wm = (wave >> 1) * 32, wn = (wave & 1) * 64;
  const int r0 = tid >> 2, c0 = (tid & 3) * 8;
  const int ca = ((tid & 3) ^ ((r0 >> 1) & 3)) * 8;
  const size_t arow = (size_t)(m0 + r0) * 2048;
  const size_t brow0 = (size_t)(n0 + r0) * 2048, brow1 = (size_t)(n0 + r0 + 64) * 2048;
  f32x4 acc[2][4];
#pragma unroll
  for (int mi = 0; mi < 2; mi++)
#pragma unroll
    for (int ni = 0; ni < 4; ni++) acc[mi][ni] = (f32x4){0.f, 0.f, 0.f, 0.f};

#pragma unroll
  for (int st = 0; st < 4; st++) {
    const int kk = st * 32 + ca;
    GLD_LDS16(&A[arow + kk], &As[st][r0 * 32 + c0]);
    GLD_LDS16(&B[brow0 + kk], &Bs[st][r0 * 32 + c0]);
    GLD_LDS16(&B[brow1 + kk], &Bs[st][(r0 + 64) * 32 + c0]);
  }

  const int sx = (l16 >> 1) & 3;
  for (int p = 0; p < P; p++) {
    if (p < P - 1) {
      __asm__ volatile("s_waitcnt vmcnt(6)" ::: "memory");
    } else {
      __asm__ volatile("s_waitcnt vmcnt(0)" ::: "memory");
    }
    raw_barrier();
#pragma unroll
    for (int j = 0; j < 2; j++) {
      const int cur = (2 * p + j) & 3;
      bf16x8 af[2], bfr[4];
#pragma unroll
      for (int mi = 0; mi < 2; mi++)
        af[mi] = *(const bf16x8*)&As[cur][(wm + mi * 16 + l16) * 32 + ((quad ^ sx) * 8)];
#pragma unroll
      for (int ni = 0; ni < 4; ni++)
        bfr[ni] = *(const bf16x8*)&Bs[cur][(wn + ni * 16 + l16) * 32 + ((quad ^ sx) * 8)];
#pragma unroll
      for (int mi = 0; mi < 2; mi++)
#pragma unroll
        for (int ni = 0; ni < 4; ni++)
          acc[mi][ni] = MFMA16(af[mi], bfr[ni], acc[mi][ni]);
    }
    __asm__ volatile("s_waitcnt lgkmcnt(0)" ::: "memory");
    raw_barrier();
    if (p < P - 2) {
#pragma unroll
      for (int j = 0; j < 2; j++) {
        const int st = 2 * p + 4 + j;
        const int slot = st & 3;
        const int kk = st * 32 + ca;
        GLD_LDS16(&A[arow + kk], &As[slot][r0 * 32 + c0]);
        GLD_LDS16(&B[brow0 + kk], &Bs[slot][r0 * 32 + c0]);
        GLD_LDS16(&B[brow1 + kk], &Bs[slot][(r0 + 64) * 32 + c0]);
      }
    }
  }
#pragma unroll
  for (int mi = 0; mi < 2; mi++)
#pragma unroll
    for (int ni = 0; ni < 4; ni++) {
      const int col = n0 + wn + ni * 16 + l16;
      const float bv = bias[col];
#pragma unroll
      for (int r = 0; r < 4; r++)
        Cs[(size_t)(m0 + wm + mi * 16 + quad * 4 + r) * N + col] =
            f2bf(acc[mi][ni][r] + bv);
    }
}

// ---------------- bf16 GEMM, 64x128 tile, ring-4, f32 out (o-proj) ----------------
__global__ __launch_bounds__(256) void gemm_db_kernel(const short* __restrict__ A,
                                                      const short* __restrict__ B,
                                                      float* __restrict__ C, int N,
                                                      int gx, int gy, int P) {
  __shared__ __align__(16) short As[4][64 * 32];
  __shared__ __align__(16) short Bs[4][128 * 32];
  const int bid = blockIdx.x;
  const int xcd = bid & 7, idx = bid >> 3;
  const int colsPerX = gx >> 1, rowsPerX = gy >> 2;
  const int xt = (xcd & 1) * colsPerX + idx % colsPerX;
  const int yt = (xcd >> 1) * rowsPerX + idx / colsPerX;
  const int tid = threadIdx.x;
  const int lane = tid & 63, wave = tid >> 6;
  const int quad = lane >> 4, l16 = lane & 15;
  const int m0 = yt * 64, n0 = xt * 128;
  const int wm = (wave >> 1) * 32, wn = (wave & 1) * 64;
  const int r0 = tid >> 2, c0 = (tid & 3) * 8;
  const int ca = ((tid & 3) ^ ((r0 >> 1) & 3)) * 8;
  const size_t arow = (size_t)(m0 + r0) * 2048;
  const size_t brow0 = (size_t)(n0 + r0) * 2048, brow1 = (size_t)(n0 + r0 + 64) * 2048;
  f32x4 acc[2][4];
#pragma unroll
  for (int mi = 0; mi < 2; mi++)
#pragma unroll
    for (int ni = 0; ni < 4; ni++) acc[mi][ni] = (f32x4){0.f, 0.f, 0.f, 0.f};

#pragma unroll
  for (int st = 0; st < 4; st++) {
    const int kk = st * 32 + ca;
    GLD_LDS16(&A[arow + kk], &As[st][r0 * 32 + c0]);
    GLD_LDS16(&B[brow0 + kk], &Bs[st][r0 * 32 + c0]);
    GLD_LDS16(&B[brow1 + kk], &Bs[st][(r0 + 64) * 32 + c0]);
  }

  const int sx = (l16 >> 1) & 3;
  for (int p = 0; p < P; p++) {
    if (p < P - 1) {
      __asm__ volatile("s_waitcnt vmcnt(6)" ::: "memory");
    } else {
      __asm__ volatile("s_waitcnt vmcnt(0)" ::: "memory");
    }
    raw_barrier();
#pragma unroll
    for (int j = 0; j < 2; j++) {
      const int cur = (2 * p + j) & 3;
      bf16x8 af[2], bfr[4];
#pragma unroll
      for (int mi = 0; mi < 2; mi++)
        af[mi] = *(const bf16x8*)&As[cur][(wm + mi * 16 + l16) * 32 + ((quad ^ sx) * 8)];
#pragma unroll
      for (int ni = 0; ni < 4; ni++)
        bfr[ni] = *(const bf16x8*)&Bs[cur][(wn + ni * 16 + l16) * 32 + ((quad ^ sx) * 8)];
#pragma unroll
      for (int mi = 0; mi < 2; mi++)
#pragma unroll
        for (int ni = 0; ni < 4; ni++)
          acc[mi][ni] = MFMA16(af[mi], bfr[ni], acc[mi][ni]);
    }
    __asm__ volatile("s_waitcnt lgkmcnt(0)" ::: "memory");
    raw_barrier();
    if (p < P - 2) {
#pragma unroll
      for (int j = 0; j < 2; j++) {
        const int st = 2 * p + 4 + j;
        const int slot = st & 3;
        const int kk = st * 32 + ca;
        GLD_LDS16(&A[arow + kk], &As[slot][r0 * 32 + c0]);
        GLD_LDS16(&B[brow0 + kk], &Bs[slot][r0 * 32 + c0]);
        GLD_LDS16(&B[brow1 + kk], &Bs[slot][(r0 + 64) * 32 + c0]);
      }
    }
  }
#pragma unroll
  for (int mi = 0; mi < 2; mi++)
#pragma unroll
    for (int ni = 0; ni < 4; ni++)
#pragma unroll
      for (int r = 0; r < 4; r++)
        C[(size_t)(m0 + wm + mi * 16 + quad * 4 + r) * N + n0 + wn + ni * 16 + l16] =
            acc[mi][ni][r];
}

// ---------------- postv_kv: K rmsnorm+rope+mask AND V mask+transpose (Q moved to attn) ----
__global__ __launch_bounds__(256) void postv_kv_kernel(
    const short* __restrict__ qkvb, const float* __restrict__ kg,
    const float* __restrict__ cosb, const float* __restrict__ sinb,
    const float* __restrict__ maskp, short* __restrict__ ko, short* __restrict__ vtb) {
  __shared__ short t[32][33];
  const int bid = blockIdx.x;
  if (bid < 1024) {  // K: 2 slots x 2048 rows, 4 rows/block
    const int rid = bid * 4 + (threadIdx.x >> 6);  // 0..4095
    const int lane = threadIdx.x & 63;
    const int slot = rid >> 11;  // 0,1
    const int bs = rid & 2047;
    const int b = bs >> 10, s = bs & 1023;
    const short* row = qkvb + (size_t)bs * 2560 + 2048 + slot * 128;
    float v0 = bf2f(row[lane]);
    float v1 = bf2f(row[64 + lane]);
    float ss = v0 * v0 + v1 * v1;
#pragma unroll
    for (int o = 1; o < 64; o <<= 1) ss += __shfl_xor(ss, o);
    float r = rsqrtf(ss * (1.0f / 128.0f) + 1e-6f);
    v0 = kg[lane] * v0 * r;
    v1 = kg[64 + lane] * v1 * r;
    int sel = (lane < 16) ? 0 : (lane < 40) ? 1 : 2;
    size_t ci = ((size_t)(sel * 2 + b) * 1024 + s) * 128 + lane;
    float c0 = cosb[ci], s0 = sinb[ci], c1 = cosb[ci + 64], s1 = sinb[ci + 64];
    const float mk = maskp[bs];
    float o0 = (v0 * c0 - v1 * s0) * mk;
    float o1 = (v1 * c1 + v0 * s1) * mk;
    short* dst = ko + (((size_t)(b * 2 + slot) * 1024) + s) * 128;
    dst[lane] = f2bf(o0);
    dst[64 + lane] = f2bf(o1);
    return;
  }
  const int b2 = bid - 1024;  // 512 V blocks
  const int d0 = (b2 & 3) * 32;
  const int s0 = ((b2 >> 2) & 31) * 32;
  const int bz = b2 >> 7;
  const int bq = bz >> 1, kv = bz & 1;
  const int tx = threadIdx.x & 31;
  const int ty = threadIdx.x >> 5;
#pragma unroll
  for (int i = 0; i < 4; i++) {
    int s = s0 + ty + i * 8;
    size_t qi = ((size_t)(bq * 1024 + s)) * 2560 + 2304 + kv * 128 + d0 + tx;
    float val = bf2f(qkvb[qi]);
    t[ty + i * 8][tx] = f2bf(val * maskp[bq * 1024 + s]);
  }
  __syncthreads();
#pragma unroll
  for (int i = 0; i < 4; i++)
    vtb[((size_t)bz * 128 + d0 + ty + i * 8) * 1024 + s0 + tx] = t[tx][ty + i * 8];
}

// ---------------- flash attention + FUSED Q-post (rmsnorm+rope in-register) ----------------
__global__ __launch_bounds__(256) void attn_kernel(
    const short* __restrict__ qkvb, const short* __restrict__ K,
    const short* __restrict__ Vt_g, const float* __restrict__ qg,
    const float* __restrict__ cosb, const float* __restrict__ sinb,
    short* __restrict__ attn) {
  const int qt = 15 - (int)blockIdx.x;
  const int h = blockIdx.y;
  const int b = blockIdx.z;
  const int nsteps = qt + 1;

  const int kv = h >> 3;
  const int tid = threadIdx.x;
  const int wave = tid >> 6, lane = tid & 63;
  const int quad = lane >> 4, l16 = lane & 15;
  __shared__ __align__(16) short Ks[2][64 * 128];
  __shared__ __align__(16) short Vs[2][128 * 64];
  __shared__ __align__(16) short Ps[4][16 * 72];

  const size_t koff = ((size_t)(b * 2 + kv) * 1024) * 128;
  const size_t voff = koff;
  const float scale = 0.08838834764831845f;  // 1/sqrt(128)

#define STAGE_KV(bf, ks0)                                                          \
  {                                                                                \
    _Pragma("unroll") for (int it = 0; it < 4; it++) {                             \
      const int c = it * 256 + tid;                                                \
      const int row = c >> 4, sl = c & 15;                                         \
      GLD_LDS16(&K[koff + (size_t)((ks0) + row) * 128 + ((sl ^ (row & 7)) * 8)],   \
                &Ks[bf][c * 8]);                                                   \
      const int d = c >> 3, sv = c & 7;                                            \
      GLD_LDS16(&Vt_g[voff + (size_t)d * 1024 + (ks0) + ((sv ^ (d & 7)) * 8)],     \
                &Vs[bf][c * 8]);                                                   \
    }                                                                              \
  }

  STAGE_KV(0, 0);  // step-0 staging in flight while Q-post computes below

  // ---- fused Q-post ----
  const int s = qt * 64 + wave * 16 + l16;  // this lane's row (seq pos)
  const short* qrow = qkvb + ((size_t)(b * 1024 + s)) * 2560 + h * 128;
  bf16x8 qraw[4];
#pragma unroll
  for (int kk = 0; kk < 4; kk++) qraw[kk] = *(const bf16x8*)&qrow[kk * 32 + quad * 8];
  float vq[4][8];
  float ss = 0.f;
#pragma unroll
  for (int kk = 0; kk < 4; kk++)
#pragma unroll
    for (int e = 0; e < 8; e++) {
      vq[kk][e] = bf2f(qraw[kk][e]);
      ss = fmaf(vq[kk][e], vq[kk][e], ss);
    }
  ss += __shfl_xor(ss, 16);
  ss += __shfl_xor(ss, 32);
  const float rr = rsqrtf(ss * (1.0f / 128.0f) + 1e-6f);
#pragma unroll
  for (int kk = 0; kk < 4; kk++) {
    float4 ga = *(const float4*)&qg[kk * 32 + quad * 8];
    float4 gb = *(const float4*)&qg[kk * 32 + quad * 8 + 4];
    vq[kk][0] *= ga.x * rr; vq[kk][1] *= ga.y * rr;
    vq[kk][2] *= ga.z * rr; vq[kk][3] *= ga.w * rr;
    vq[kk][4] *= gb.x * rr; vq[kk][5] *= gb.y * rr;
    vq[kk][6] *= gb.z * rr; vq[kk][7] *= gb.w * rr;
  }
  bf16x8 aq[4];
#pragma unroll
  for (int kk = 0; kk < 2; kk++) {  // rope pair (kk, kk+2): dims d and d+64
    const int dbase = kk * 32 + quad * 8;  // < 64; 8-group doesn't straddle 16/40
    const int sel = (dbase < 16) ? 0 : (dbase < 40) ? 1 : 2;
    const size_t ci = ((size_t)(sel * 2 + b) * 1024 + s) * 128 + dbase;
    float cd[8], sd[8], cD[8], sD[8];
    {
      float4 a0 = *(const float4*)&cosb[ci], a1 = *(const float4*)&cosb[ci + 4];
      cd[0]=a0.x; cd[1]=a0.y; cd[2]=a0.z; cd[3]=a0.w;
      cd[4]=a1.x; cd[5]=a1.y; cd[6]=a1.z; cd[7]=a1.w;
    }
    {
      float4 a0 = *(const float4*)&sinb[ci], a1 = *(const float4*)&sinb[ci + 4];
      sd[0]=a0.x; sd[1]=a0.y; sd[2]=a0.z; sd[3]=a0.w;
      sd[4]=a1.x; sd[5]=a1.y; sd[6]=a1.z; sd[7]=a1.w;
    }
    {
      float4 a0 = *(const float4*)&cosb[ci + 64], a1 = *(const float4*)&cosb[ci + 68];
      cD[0]=a0.x; cD[1]=a0.y; cD[2]=a0.z; cD[3]=a0.w;
      cD[4]=a1.x; cD[5]=a1.y; cD[6]=a1.z; cD[7]=a1.w;
    }
    {
      float4 a0 = *(const float4*)&sinb[ci + 64], a1 = *(const float4*)&sinb[ci + 68];
      sD[0]=a0.x; sD[1]=a0.y; sD[2]=a0.z; sD[3]=a0.w;
      sD[4]=a1.x; sD[5]=a1.y; sD[6]=a1.z; sD[7]=a1.w;
    }
#pragma unroll
    for (int e = 0; e < 8; e++) {
      aq[kk][e] = f2bf(vq[kk][e] * cd[e] - vq[kk + 2][e] * sd[e]);
      aq[kk + 2][e] = f2bf(vq[kk + 2][e] * cD[e] + vq[kk][e] * sD[e]);
    }
  }

  f32x4 o[8];
#pragma unroll
  for (int i = 0; i < 8; i++) o[i] = (f32x4){0.f, 0.f, 0.f, 0.f};
  float l[4] = {0.f, 0.f, 0.f, 0.f};
  const int qrow0 = qt * 64 + wave * 16 + quad * 4;

  for (int st = 0; st < nsteps; st++) {
    __asm__ volatile("s_waitcnt vmcnt(0)" ::: "memory");
    raw_barrier();
    if (st + 1 < nsteps) { STAGE_KV((st + 1) & 1, (st + 1) * 64); }
    const int cb = st & 1;
    const int ks0 = st * 64;
    f32x4 sc[4];
#pragma unroll
    for (int nt = 0; nt < 4; nt++) sc[nt] = (f32x4){0.f, 0.f, 0.f, 0.f};
    __builtin_amdgcn_s_setprio(1);
#pragma unroll
    for (int nt = 0; nt < 4; nt++) {
      const int rrK = nt * 16 + l16;
#pragma unroll
      for (int kk = 0; kk < 4; kk++) {
        bf16x8 bk = *(const bf16x8*)&Ks[cb][rrK * 128 + (((kk * 4 + quad) ^ (rrK & 7)) * 8)];
        sc[nt] = MFMA16(aq[kk], bk, sc[nt]);
      }
    }
    __builtin_amdgcn_s_setprio(0);
    // fixed-shift softmax weights: p = exp(s*scale - 12), causal-masked to 0
    short* P = &Ps[wave][0];
#pragma unroll
    for (int nt = 0; nt < 4; nt++) {
      const int kcol = ks0 + nt * 16 + l16;
#pragma unroll
      for (int r = 0; r < 4; r++) {
        float p = (kcol > qrow0 + r) ? 0.f : __expf(fmaf(sc[nt][r], scale, -12.0f));
        l[r] += p;
        P[(quad * 4 + r) * 72 + nt * 16 + l16] = f2bf(p);
      }
    }
    __asm__ volatile("s_waitcnt lgkmcnt(0)" ::: "memory");
    bf16x8 pa0 = *(const bf16x8*)&P[l16 * 72 + quad * 8];
    bf16x8 pa1 = *(const bf16x8*)&P[l16 * 72 + 32 + quad * 8];
    __builtin_amdgcn_s_setprio(1);
#pragma unroll
    for (int nt = 0; nt < 8; nt++) {
      const int rrV = nt * 16 + l16;
      bf16x8 bv0 = *(const bf16x8*)&Vs[cb][rrV * 64 + ((quad ^ (rrV & 7)) * 8)];
      bf16x8 bv1 = *(const bf16x8*)&Vs[cb][rrV * 64 + (((4 + quad) ^ (rrV & 7)) * 8)];
      o[nt] = MFMA16(pa0, bv0, o[nt]);
      o[nt] = MFMA16(pa1, bv1, o[nt]);
    }
    __builtin_amdgcn_s_setprio(0);
  }
#undef STAGE_KV
#pragma unroll
  for (int off = 1; off < 16; off <<= 1)
#pragma unroll
    for (int r = 0; r < 4; r++) l[r] += __shfl_xor(l[r], off);
  float inv[4];
#pragma unroll
  for (int r = 0; r < 4; r++) inv[r] = 1.f / l[r];
  const int lrow = wave * 16 + quad * 4;
  short* dst = attn + ((size_t)(b * 1024 + qt * 64 + lrow)) * 2048 + h * 128;
#pragma unroll
  for (int nt = 0; nt < 8; nt++)
#pragma unroll
    for (int r = 0; r < 4; r++)
      dst[(size_t)r * 2048 + nt * 16 + l16] = f2bf(o[nt][r] * inv[r]);
}

extern "C" void kernel_launch(void* const* d_in, const int* in_sizes, int n_in,
                              void* d_out, int out_size, void* d_ws, size_t ws_size,
                              hipStream_t stream) {
  const float* x = (const float*)d_in[0];
  const float* cosb = (const float*)d_in[1];
  const float* sinb = (const float*)d_in[2];
  const float* mask = (const float*)d_in[3];
  const float* q_w = (const float*)d_in[4];
  const float* q_b = (const float*)d_in[5];
  const float* k_w = (const float*)d_in[6];
  const float* k_b = (const float*)d_in[7];
  const float* v_w = (const float*)d_in[8];
  const float* v_b = (const float*)d_in[9];
  const float* qg = (const float*)d_in[10];
  const float* kg = (const float*)d_in[11];
  const float* o_w = (const float*)d_in[12];
  float* out = (float*)d_out;

  char* ws = (char*)d_ws;
  short* wo_t = (short*)(ws);                              // [0,8) MB
  short* wqkv_t = (short*)(ws + ((size_t)8 << 20));        // [8,18.4) MB (dead after gemm)
  short* attn = (short*)(ws + ((size_t)9 << 20));          // aliases wqkv_t (after gemm)
  short* xb = (short*)(ws + ((size_t)18 << 20));           // [18,26.4) MB
  short* kb = (short*)(ws + ((size_t)46 << 20));           // [46,47)
  short* vtb = (short*)(ws + ((size_t)47 << 20));          // [47,48)
  short* qkvb = (short*)(ws + ((size_t)48 << 20));         // [48,58.4) MB bf16 qkv
  float* biasAll = (float*)(ws + ((size_t)68 << 20));      // 10 KB fused bias

  prep_kernel<<<6401, 256, 0, stream>>>(x, q_w, k_w, v_w, o_w, q_b, k_b, v_b, xb,
                                        wqkv_t, wo_t, biasAll);
  gemm_qkv_kernel<<<640, 256, 0, stream>>>(xb, wqkv_t, qkvb, biasAll, 2560, 20, 32, 32);
  postv_kv_kernel<<<1536, 256, 0, stream>>>(qkvb, kg, cosb, sinb, mask, kb, vtb);
  attn_kernel<<<dim3(16, 16, 2), 256, 0, stream>>>(qkvb, kb, vtb, qg, cosb, sinb, attn);
  gemm_db_kernel<<<512, 256, 0, stream>>>(attn, wo_t, out, 2048, 16, 32, 32);
}

// Round 15
// 214.050 us; speedup vs baseline: 1.0557x; 1.0370x over previous
//
#include <hip/hip_runtime.h>

typedef __attribute__((ext_vector_type(8))) short bf16x8;
typedef __attribute__((ext_vector_type(4))) float f32x4;

#define MFMA16(a, b, c) __builtin_amdgcn_mfma_f32_16x16x32_bf16(a, b, c, 0, 0, 0)

__device__ inline short f2bf(float f) {
  union { float f; unsigned u; } v;
  v.f = f;
  unsigned r = v.u + 0x7FFF + ((v.u >> 16) & 1);
  return (short)(r >> 16);
}
__device__ inline float bf2f(short s) {
  union { unsigned u; float f; } v;
  v.u = ((unsigned)(unsigned short)s) << 16;
  return v.f;
}
#define GLD_LDS16(g, l)                                                        \
  __builtin_amdgcn_global_load_lds(                                            \
      (const __attribute__((address_space(1))) unsigned int*)(g),              \
      (__attribute__((address_space(3))) unsigned int*)(l), 16, 0, 0)

__device__ __forceinline__ void raw_barrier() {
  __asm__ volatile("" ::: "memory");
  __builtin_amdgcn_s_barrier();
  __asm__ volatile("" ::: "memory");
}

// ---------------- prep: x->bf16 + weight transposes + fused qkv bias vector ----------------
__global__ __launch_bounds__(256) void prep_kernel(
    const float* __restrict__ x, const float* __restrict__ q_w,
    const float* __restrict__ k_w, const float* __restrict__ v_w,
    const float* __restrict__ o_w, const float* __restrict__ q_b,
    const float* __restrict__ k_b, const float* __restrict__ v_b,
    short* __restrict__ xb, short* __restrict__ wqkv_t, short* __restrict__ wo_t,
    float* __restrict__ biasAll) {
  __shared__ float t[64][65];
  int bid = blockIdx.x;
  if (bid == 6400) {  // fused bias vector [q_b | k_b | v_b]
    for (int i = threadIdx.x; i < 2560; i += 256) {
      float v = (i < 2048) ? q_b[i] : (i < 2304 ? k_b[i - 2048] : v_b[i - 2304]);
      biasAll[i] = v;
    }
    return;
  }
  if (bid < 4096) {  // cvt x
    int i = (bid * 256 + threadIdx.x) * 4;
    float4 f = *(const float4*)&x[i];
    short4 o;
    o.x = f2bf(f.x); o.y = f2bf(f.y); o.z = f2bf(f.z); o.w = f2bf(f.w);
    *(short4*)&xb[i] = o;
    return;
  }
  bid -= 4096;
  const float* src;
  short* dst;
  int C, bx, by;
  if (bid < 1024) {
    src = q_w; dst = wqkv_t; C = 2048;
    bx = (bid & 31) * 64; by = (bid >> 5) * 64;
  } else if (bid < 1152) {
    bid -= 1024;
    src = k_w; dst = wqkv_t + (size_t)2048 * 2048; C = 256;
    bx = (bid & 3) * 64; by = (bid >> 2) * 64;
  } else if (bid < 1280) {
    bid -= 1152;
    src = v_w; dst = wqkv_t + (size_t)2304 * 2048; C = 256;
    bx = (bid & 3) * 64; by = (bid >> 2) * 64;
  } else {
    bid -= 1280;
    src = o_w; dst = wo_t; C = 2048;
    bx = (bid & 31) * 64; by = (bid >> 5) * 64;
  }
  const int R = 2048;
  const int tx = threadIdx.x & 15;
  const int ty = threadIdx.x >> 4;
#pragma unroll
  for (int i = 0; i < 4; i++) {
    int row = ty + i * 16;
    float4 f = *(const float4*)&src[(size_t)(by + row) * C + bx + tx * 4];
    t[row][tx * 4 + 0] = f.x;
    t[row][tx * 4 + 1] = f.y;
    t[row][tx * 4 + 2] = f.z;
    t[row][tx * 4 + 3] = f.w;
  }
  __syncthreads();
#pragma unroll
  for (int i = 0; i < 4; i++) {
    int c = ty + i * 16;
    short4 o;
    o.x = f2bf(t[tx * 4 + 0][c]);
    o.y = f2bf(t[tx * 4 + 1][c]);
    o.z = f2bf(t[tx * 4 + 2][c]);
    o.w = f2bf(t[tx * 4 + 3][c]);
    *(short4*)&dst[(size_t)(bx + c) * R + by + tx * 4] = o;
  }
}

// ---------------- QKV GEMM: 64x128 tile, ring-4, bias + bf16 epilogue ----------------
__global__ __launch_bounds__(256) void gemm_qkv_kernel(const short* __restrict__ A,
                                                       const short* __restrict__ B,
                                                       short* __restrict__ Cs,
                                                       const float* __restrict__ bias,
                                                       int N, int gx, int gy, int P) {
  __shared__ __align__(16) short As[4][64 * 32];
  __shared__ __align__(16) short Bs[4][128 * 32];
  const int bid = blockIdx.x;
  const int xcd = bid & 7, idx = bid >> 3;
  const int colsPerX = gx >> 1, rowsPerX = gy >> 2;
  const int xt = (xcd & 1) * colsPerX + idx % colsPerX;
  const int yt = (xcd >> 1) * rowsPerX + idx / colsPerX;
  const int tid = threadIdx.x;
  const int lane = tid & 63, wave = tid >> 6;
  const int quad = lane >> 4, l16 = lane & 15;
  const int m0 = yt * 64, n0 = xt * 128;
  const int wm = (wave >> 1) * 32, wn = (wave & 1) * 64;
  const int r0 = tid >> 2, c0 = (tid & 3) * 8;
  const int ca = ((tid & 3) ^ ((r0 >> 1) & 3)) * 8;
  const size_t arow = (size_t)(m0 + r0) * 2048;
  const size_t brow0 = (size_t)(n0 + r0) * 2048, brow1 = (size_t)(n0 + r0 + 64) * 2048;
  f32x4 acc[2][4];
#pragma unroll
  for (int mi = 0; mi < 2; mi++)
#pragma unroll
    for (int ni = 0; ni < 4; ni++) acc[mi][ni] = (f32x4){0.f, 0.f, 0.f, 0.f};

#pragma unroll
  for (int st = 0; st < 4; st++) {
    const int kk = st * 32 + ca;
    GLD_LDS16(&A[arow + kk], &As[st][r0 * 32 + c0]);
    GLD_LDS16(&B[brow0 + kk], &Bs[st][r0 * 32 + c0]);
    GLD_LDS16(&B[brow1 + kk], &Bs[st][(r0 + 64) * 32 + c0]);
  }

  const int sx = (l16 >> 1) & 3;
  for (int p = 0; p < P; p++) {
    if (p < P - 1) {
      __asm__ volatile("s_waitcnt vmcnt(6)" ::: "memory");
    } else {
      __asm__ volatile("s_waitcnt vmcnt(0)" ::: "memory");
    }
    raw_barrier();
#pragma unroll
    for (int j = 0; j < 2; j++) {
      const int cur = (2 * p + j) & 3;
      bf16x8 af[2], bfr[4];
#pragma unroll
      for (int mi = 0; mi < 2; mi++)
        af[mi] = *(const bf16x8*)&As[cur][(wm + mi * 16 + l16) * 32 + ((quad ^ sx) * 8)];
#pragma unroll
      for (int ni = 0; ni < 4; ni++)
        bfr[ni] = *(const bf16x8*)&Bs[cur][(wn + ni * 16 + l16) * 32 + ((quad ^ sx) * 8)];
#pragma unroll
      for (int mi = 0; mi < 2; mi++)
#pragma unroll
        for (int ni = 0; ni < 4; ni++)
          acc[mi][ni] = MFMA16(af[mi], bfr[ni], acc[mi][ni]);
    }
    __asm__ volatile("s_waitcnt lgkmcnt(0)" ::: "memory");
    raw_barrier();
    if (p < P - 2) {
#pragma unroll
      for (int j = 0; j < 2; j++) {
        const int st = 2 * p + 4 + j;
        const int slot = st & 3;
        const int kk = st * 32 + ca;
        GLD_LDS16(&A[arow + kk], &As[slot][r0 * 32 + c0]);
        GLD_LDS16(&B[brow0 + kk], &Bs[slot][r0 * 32 + c0]);
        GLD_LDS16(&B[brow1 + kk], &Bs[slot][(r0 + 64) * 32 + c0]);
      }
    }
  }
#pragma unroll
  for (int mi = 0; mi < 2; mi++)
#pragma unroll
    for (int ni = 0; ni < 4; ni++) {
      const int col = n0 + wn + ni * 16 + l16;
      const float bv = bias[col];
#pragma unroll
      for (int r = 0; r < 4; r++)
        Cs[(size_t)(m0 + wm + mi * 16 + quad * 4 + r) * N + col] =
            f2bf(acc[mi][ni][r] + bv);
    }
}

// ---------------- bf16 GEMM, 64x128 tile, ring-4, f32 out (o-proj) ----------------
__global__ __launch_bounds__(256) void gemm_db_kernel(const short* __restrict__ A,
                                                      const short* __restrict__ B,
                                                      float* __restrict__ C, int N,
                                                      int gx, int gy, int P) {
  __shared__ __align__(16) short As[4][64 * 32];
  __shared__ __align__(16) short Bs[4][128 * 32];
  const int bid = blockIdx.x;
  const int xcd = bid & 7, idx = bid >> 3;
  const int colsPerX = gx >> 1, rowsPerX = gy >> 2;
  const int xt = (xcd & 1) * colsPerX + idx % colsPerX;
  const int yt = (xcd >> 1) * rowsPerX + idx / colsPerX;
  const int tid = threadIdx.x;
  const int lane = tid & 63, wave = tid >> 6;
  const int quad = lane >> 4, l16 = lane & 15;
  const int m0 = yt * 64, n0 = xt * 128;
  const int wm = (wave >> 1) * 32, wn = (wave & 1) * 64;
  const int r0 = tid >> 2, c0 = (tid & 3) * 8;
  const int ca = ((tid & 3) ^ ((r0 >> 1) & 3)) * 8;
  const size_t arow = (size_t)(m0 + r0) * 2048;
  const size_t brow0 = (size_t)(n0 + r0) * 2048, brow1 = (size_t)(n0 + r0 + 64) * 2048;
  f32x4 acc[2][4];
#pragma unroll
  for (int mi = 0; mi < 2; mi++)
#pragma unroll
    for (int ni = 0; ni < 4; ni++) acc[mi][ni] = (f32x4){0.f, 0.f, 0.f, 0.f};

#pragma unroll
  for (int st = 0; st < 4; st++) {
    const int kk = st * 32 + ca;
    GLD_LDS16(&A[arow + kk], &As[st][r0 * 32 + c0]);
    GLD_LDS16(&B[brow0 + kk], &Bs[st][r0 * 32 + c0]);
    GLD_LDS16(&B[brow1 + kk], &Bs[st][(r0 + 64) * 32 + c0]);
  }

  const int sx = (l16 >> 1) & 3;
  for (int p = 0; p < P; p++) {
    if (p < P - 1) {
      __asm__ volatile("s_waitcnt vmcnt(6)" ::: "memory");
    } else {
      __asm__ volatile("s_waitcnt vmcnt(0)" ::: "memory");
    }
    raw_barrier();
#pragma unroll
    for (int j = 0; j < 2; j++) {
      const int cur = (2 * p + j) & 3;
      bf16x8 af[2], bfr[4];
#pragma unroll
      for (int mi = 0; mi < 2; mi++)
        af[mi] = *(const bf16x8*)&As[cur][(wm + mi * 16 + l16) * 32 + ((quad ^ sx) * 8)];
#pragma unroll
      for (int ni = 0; ni < 4; ni++)
        bfr[ni] = *(const bf16x8*)&Bs[cur][(wn + ni * 16 + l16) * 32 + ((quad ^ sx) * 8)];
#pragma unroll
      for (int mi = 0; mi < 2; mi++)
#pragma unroll
        for (int ni = 0; ni < 4; ni++)
          acc[mi][ni] = MFMA16(af[mi], bfr[ni], acc[mi][ni]);
    }
    __asm__ volatile("s_waitcnt lgkmcnt(0)" ::: "memory");
    raw_barrier();
    if (p < P - 2) {
#pragma unroll
      for (int j = 0; j < 2; j++) {
        const int st = 2 * p + 4 + j;
        const int slot = st & 3;
        const int kk = st * 32 + ca;
        GLD_LDS16(&A[arow + kk], &As[slot][r0 * 32 + c0]);
        GLD_LDS16(&B[brow0 + kk], &Bs[slot][r0 * 32 + c0]);
        GLD_LDS16(&B[brow1 + kk], &Bs[slot][(r0 + 64) * 32 + c0]);
      }
    }
  }
#pragma unroll
  for (int mi = 0; mi < 2; mi++)
#pragma unroll
    for (int ni = 0; ni < 4; ni++)
#pragma unroll
      for (int r = 0; r < 4; r++)
        C[(size_t)(m0 + wm + mi * 16 + quad * 4 + r) * N + n0 + wn + ni * 16 + l16] =
            acc[mi][ni][r];
}

// ---------------- postv_kv: K rmsnorm+rope+mask AND V mask+transpose (Q moved to attn) ----
__global__ __launch_bounds__(256) void postv_kv_kernel(
    const short* __restrict__ qkvb, const float* __restrict__ kg,
    const float* __restrict__ cosb, const float* __restrict__ sinb,
    const float* __restrict__ maskp, short* __restrict__ ko, short* __restrict__ vtb) {
  __shared__ short t[32][33];
  const int bid = blockIdx.x;
  if (bid < 1024) {  // K: 2 slots x 2048 rows, 4 rows/block
    const int rid = bid * 4 + (threadIdx.x >> 6);  // 0..4095
    const int lane = threadIdx.x & 63;
    const int slot = rid >> 11;  // 0,1
    const int bs = rid & 2047;
    const int b = bs >> 10, s = bs & 1023;
    const short* row = qkvb + (size_t)bs * 2560 + 2048 + slot * 128;
    float v0 = bf2f(row[lane]);
    float v1 = bf2f(row[64 + lane]);
    float ss = v0 * v0 + v1 * v1;
#pragma unroll
    for (int o = 1; o < 64; o <<= 1) ss += __shfl_xor(ss, o);
    float r = rsqrtf(ss * (1.0f / 128.0f) + 1e-6f);
    v0 = kg[lane] * v0 * r;
    v1 = kg[64 + lane] * v1 * r;
    int sel = (lane < 16) ? 0 : (lane < 40) ? 1 : 2;
    size_t ci = ((size_t)(sel * 2 + b) * 1024 + s) * 128 + lane;
    float c0 = cosb[ci], s0 = sinb[ci], c1 = cosb[ci + 64], s1 = sinb[ci + 64];
    const float mk = maskp[bs];
    float o0 = (v0 * c0 - v1 * s0) * mk;
    float o1 = (v1 * c1 + v0 * s1) * mk;
    short* dst = ko + (((size_t)(b * 2 + slot) * 1024) + s) * 128;
    dst[lane] = f2bf(o0);
    dst[64 + lane] = f2bf(o1);
    return;
  }
  const int b2 = bid - 1024;  // 512 V blocks
  const int d0 = (b2 & 3) * 32;
  const int s0 = ((b2 >> 2) & 31) * 32;
  const int bz = b2 >> 7;
  const int bq = bz >> 1, kv = bz & 1;
  const int tx = threadIdx.x & 31;
  const int ty = threadIdx.x >> 5;
#pragma unroll
  for (int i = 0; i < 4; i++) {
    int s = s0 + ty + i * 8;
    size_t qi = ((size_t)(bq * 1024 + s)) * 2560 + 2304 + kv * 128 + d0 + tx;
    float val = bf2f(qkvb[qi]);
    t[ty + i * 8][tx] = f2bf(val * maskp[bq * 1024 + s]);
  }
  __syncthreads();
#pragma unroll
  for (int i = 0; i < 4; i++)
    vtb[((size_t)bz * 128 + d0 + ty + i * 8) * 1024 + s0 + tx] = t[tx][ty + i * 8];
}

// ---------------- flash attention + FUSED Q-post (rmsnorm+rope in-register) ----------------
// Antithetic qt pairing: all 512 blocks are co-resident (2/CU, no dynamic refill) and the
// dispatcher round-robins, so CU c gets blocks c and c+256 = same (x,y), z=0/1. Mapping
// z=0 -> qt=15-x and z=1 -> qt=x makes each CU's pair sum to 17 steps (was: same qt twice,
// 2..32-step imbalance, ~32-step makespan).
__global__ __launch_bounds__(256) void attn_kernel(
    const short* __restrict__ qkvb, const short* __restrict__ K,
    const short* __restrict__ Vt_g, const float* __restrict__ qg,
    const float* __restrict__ cosb, const float* __restrict__ sinb,
    short* __restrict__ attn) {
  const int b = blockIdx.z;
  const int qt = b ? (int)blockIdx.x : 15 - (int)blockIdx.x;
  const int h = blockIdx.y;
  const int nsteps = qt + 1;

  const int kv = h >> 3;
  const int tid = threadIdx.x;
  const int wave = tid >> 6, lane = tid & 63;
  const int quad = lane >> 4, l16 = lane & 15;
  __shared__ __align__(16) short Ks[2][64 * 128];
  __shared__ __align__(16) short Vs[2][128 * 64];
  __shared__ __align__(16) short Ps[4][16 * 72];

  const size_t koff = ((size_t)(b * 2 + kv) * 1024) * 128;
  const size_t voff = koff;
  const float scale = 0.08838834764831845f;  // 1/sqrt(128)

#define STAGE_KV(bf, ks0)                                                          \
  {                                                                                \
    _Pragma("unroll") for (int it = 0; it < 4; it++) {                             \
      const int c = it * 256 + tid;                                                \
      const int row = c >> 4, sl = c & 15;                                         \
      GLD_LDS16(&K[koff + (size_t)((ks0) + row) * 128 + ((sl ^ (row & 7)) * 8)],   \
                &Ks[bf][c * 8]);                                                   \
      const int d = c >> 3, sv = c & 7;                                            \
      GLD_LDS16(&Vt_g[voff + (size_t)d * 1024 + (ks0) + ((sv ^ (d & 7)) * 8)],     \
                &Vs[bf][c * 8]);                                                   \
    }                                                                              \
  }

  STAGE_KV(0, 0);  // step-0 staging in flight while Q-post computes below

  // ---- fused Q-post ----
  const int s = qt * 64 + wave * 16 + l16;  // this lane's row (seq pos)
  const short* qrow = qkvb + ((size_t)(b * 1024 + s)) * 2560 + h * 128;
  bf16x8 qraw[4];
#pragma unroll
  for (int kk = 0; kk < 4; kk++) qraw[kk] = *(const bf16x8*)&qrow[kk * 32 + quad * 8];
  float vq[4][8];
  float ss = 0.f;
#pragma unroll
  for (int kk = 0; kk < 4; kk++)
#pragma unroll
    for (int e = 0; e < 8; e++) {
      vq[kk][e] = bf2f(qraw[kk][e]);
      ss = fmaf(vq[kk][e], vq[kk][e], ss);
    }
  ss += __shfl_xor(ss, 16);
  ss += __shfl_xor(ss, 32);
  const float rr = rsqrtf(ss * (1.0f / 128.0f) + 1e-6f);
#pragma unroll
  for (int kk = 0; kk < 4; kk++) {
    float4 ga = *(const float4*)&qg[kk * 32 + quad * 8];
    float4 gb = *(const float4*)&qg[kk * 32 + quad * 8 + 4];
    vq[kk][0] *= ga.x * rr; vq[kk][1] *= ga.y * rr;
    vq[kk][2] *= ga.z * rr; vq[kk][3] *= ga.w * rr;
    vq[kk][4] *= gb.x * rr; vq[kk][5] *= gb.y * rr;
    vq[kk][6] *= gb.z * rr; vq[kk][7] *= gb.w * rr;
  }
  bf16x8 aq[4];
#pragma unroll
  for (int kk = 0; kk < 2; kk++) {  // rope pair (kk, kk+2): dims d and d+64
    const int dbase = kk * 32 + quad * 8;  // < 64; 8-group doesn't straddle 16/40
    const int sel = (dbase < 16) ? 0 : (dbase < 40) ? 1 : 2;
    const size_t ci = ((size_t)(sel * 2 + b) * 1024 + s) * 128 + dbase;
    float cd[8], sd[8], cD[8], sD[8];
    {
      float4 a0 = *(const float4*)&cosb[ci], a1 = *(const float4*)&cosb[ci + 4];
      cd[0]=a0.x; cd[1]=a0.y; cd[2]=a0.z; cd[3]=a0.w;
      cd[4]=a1.x; cd[5]=a1.y; cd[6]=a1.z; cd[7]=a1.w;
    }
    {
      float4 a0 = *(const float4*)&sinb[ci], a1 = *(const float4*)&sinb[ci + 4];
      sd[0]=a0.x; sd[1]=a0.y; sd[2]=a0.z; sd[3]=a0.w;
      sd[4]=a1.x; sd[5]=a1.y; sd[6]=a1.z; sd[7]=a1.w;
    }
    {
      float4 a0 = *(const float4*)&cosb[ci + 64], a1 = *(const float4*)&cosb[ci + 68];
      cD[0]=a0.x; cD[1]=a0.y; cD[2]=a0.z; cD[3]=a0.w;
      cD[4]=a1.x; cD[5]=a1.y; cD[6]=a1.z; cD[7]=a1.w;
    }
    {
      float4 a0 = *(const float4*)&sinb[ci + 64], a1 = *(const float4*)&sinb[ci + 68];
      sD[0]=a0.x; sD[1]=a0.y; sD[2]=a0.z; sD[3]=a0.w;
      sD[4]=a1.x; sD[5]=a1.y; sD[6]=a1.z; sD[7]=a1.w;
    }
#pragma unroll
    for (int e = 0; e < 8; e++) {
      aq[kk][e] = f2bf(vq[kk][e] * cd[e] - vq[kk + 2][e] * sd[e]);
      aq[kk + 2][e] = f2bf(vq[kk + 2][e] * cD[e] + vq[kk][e] * sD[e]);
    }
  }

  f32x4 o[8];
#pragma unroll
  for (int i = 0; i < 8; i++) o[i] = (f32x4){0.f, 0.f, 0.f, 0.f};
  float l[4] = {0.f, 0.f, 0.f, 0.f};
  const int qrow0 = qt * 64 + wave * 16 + quad * 4;

  for (int st = 0; st < nsteps; st++) {
    __asm__ volatile("s_waitcnt vmcnt(0)" ::: "memory");
    raw_barrier();
    if (st + 1 < nsteps) { STAGE_KV((st + 1) & 1, (st + 1) * 64); }
    const int cb = st & 1;
    const int ks0 = st * 64;
    f32x4 sc[4];
#pragma unroll
    for (int nt = 0; nt < 4; nt++) sc[nt] = (f32x4){0.f, 0.f, 0.f, 0.f};
    __builtin_amdgcn_s_setprio(1);
#pragma unroll
    for (int nt = 0; nt < 4; nt++) {
      const int rrK = nt * 16 + l16;
#pragma unroll
      for (int kk = 0; kk < 4; kk++) {
        bf16x8 bk = *(const bf16x8*)&Ks[cb][rrK * 128 + (((kk * 4 + quad) ^ (rrK & 7)) * 8)];
        sc[nt] = MFMA16(aq[kk], bk, sc[nt]);
      }
    }
    __builtin_amdgcn_s_setprio(0);
    // fixed-shift softmax weights: p = exp(s*scale - 12), causal-masked to 0
    short* P = &Ps[wave][0];
#pragma unroll
    for (int nt = 0; nt < 4; nt++) {
      const int kcol = ks0 + nt * 16 + l16;
#pragma unroll
      for (int r = 0; r < 4; r++) {
        float p = (kcol > qrow0 + r) ? 0.f : __expf(fmaf(sc[nt][r], scale, -12.0f));
        l[r] += p;
        P[(quad * 4 + r) * 72 + nt * 16 + l16] = f2bf(p);
      }
    }
    __asm__ volatile("s_waitcnt lgkmcnt(0)" ::: "memory");
    bf16x8 pa0 = *(const bf16x8*)&P[l16 * 72 + quad * 8];
    bf16x8 pa1 = *(const bf16x8*)&P[l16 * 72 + 32 + quad * 8];
    __builtin_amdgcn_s_setprio(1);
#pragma unroll
    for (int nt = 0; nt < 8; nt++) {
      const int rrV = nt * 16 + l16;
      bf16x8 bv0 = *(const bf16x8*)&Vs[cb][rrV * 64 + ((quad ^ (rrV & 7)) * 8)];
      bf16x8 bv1 = *(const bf16x8*)&Vs[cb][rrV * 64 + (((4 + quad) ^ (rrV & 7)) * 8)];
      o[nt] = MFMA16(pa0, bv0, o[nt]);
      o[nt] = MFMA16(pa1, bv1, o[nt]);
    }
    __builtin_amdgcn_s_setprio(0);
  }
#undef STAGE_KV
#pragma unroll
  for (int off = 1; off < 16; off <<= 1)
#pragma unroll
    for (int r = 0; r < 4; r++) l[r] += __shfl_xor(l[r], off);
  float inv[4];
#pragma unroll
  for (int r = 0; r < 4; r++) inv[r] = 1.f / l[r];
  const int lrow = wave * 16 + quad * 4;
  short* dst = attn + ((size_t)(b * 1024 + qt * 64 + lrow)) * 2048 + h * 128;
#pragma unroll
  for (int nt = 0; nt < 8; nt++)
#pragma unroll
    for (int r = 0; r < 4; r++)
      dst[(size_t)r * 2048 + nt * 16 + l16] = f2bf(o[nt][r] * inv[r]);
}

extern "C" void kernel_launch(void* const* d_in, const int* in_sizes, int n_in,
                              void* d_out, int out_size, void* d_ws, size_t ws_size,
                              hipStream_t stream) {
  const float* x = (const float*)d_in[0];
  const float* cosb = (const float*)d_in[1];
  const float* sinb = (const float*)d_in[2];
  const float* mask = (const float*)d_in[3];
  const float* q_w = (const float*)d_in[4];
  const float* q_b = (const float*)d_in[5];
  const float* k_w = (const float*)d_in[6];
  const float* k_b = (const float*)d_in[7];
  const float* v_w = (const float*)d_in[8];
  const float* v_b = (const float*)d_in[9];
  const float* qg = (const float*)d_in[10];
  const float* kg = (const float*)d_in[11];
  const float* o_w = (const float*)d_in[12];
  float* out = (float*)d_out;

  char* ws = (char*)d_ws;
  short* wo_t = (short*)(ws);                              // [0,8) MB
  short* wqkv_t = (short*)(ws + ((size_t)8 << 20));        // [8,18.4) MB (dead after gemm)
  short* attn = (short*)(ws + ((size_t)9 << 20));          // aliases wqkv_t (after gemm)
  short* xb = (short*)(ws + ((size_t)18 << 20));           // [18,26.4) MB
  short* kb = (short*)(ws + ((size_t)46 << 20));           // [46,47)
  short* vtb = (short*)(ws + ((size_t)47 << 20));          // [47,48)
  short* qkvb = (short*)(ws + ((size_t)48 << 20));         // [48,58.4) MB bf16 qkv
  float* biasAll = (float*)(ws + ((size_t)68 << 20));      // 10 KB fused bias

  prep_kernel<<<6401, 256, 0, stream>>>(x, q_w, k_w, v_w, o_w, q_b, k_b, v_b, xb,
                                        wqkv_t, wo_t, biasAll);
  gemm_qkv_kernel<<<640, 256, 0, stream>>>(xb, wqkv_t, qkvb, biasAll, 2560, 20, 32, 32);
  postv_kv_kernel<<<1536, 256, 0, stream>>>(qkvb, kg, cosb, sinb, mask, kb, vtb);
  attn_kernel<<<dim3(16, 16, 2), 256, 0, stream>>>(qkvb, kb, vtb, qg, cosb, sinb, attn);
  gemm_db_kernel<<<512, 256, 0, stream>>>(attn, wo_t, out, 2048, 16, 32, 32);
}